// Round 2
// baseline (237.332 us; speedup 1.0000x reference)
//
#include <hip/hip_runtime.h>

// 8x8 block DCT: C = A * B * A^T per non-overlapping block.
// R2: stores staged through LDS (32 KiB, two 128-thread half-phases) so global
// writes are fully coalesced 4 KiB/instruction. LDS float4 index XOR-swizzled
// (f4 ^ ((f4>>4)&15)) -> <=2-way bank conflicts on write and read (2-way free).
// R3/R4: output stores are NONTEMPORAL via native ext_vector_type float4
// (__builtin_nontemporal_store rejects HIP_vector_type). Input (128MB) +
// output (128MB) together exactly fill the 256MB Infinity Cache; the output is
// write-once/never-read, so letting it allocate evicts the input between bench
// iterations. nt stores keep the write stream out of the cache hierarchy ->
// input stays L3-resident across iterations -> FETCH_SIZE should collapse.

typedef float f32x4 __attribute__((ext_vector_type(4)));

__global__ __launch_bounds__(256, 5) void dct8x8_kernel(const float* __restrict__ x,
                                                        float* __restrict__ out) {
    constexpr float A[8][8] = {
        { 0.35355339059327373f,  0.35355339059327373f,  0.35355339059327373f,  0.35355339059327373f,
          0.35355339059327373f,  0.35355339059327373f,  0.35355339059327373f,  0.35355339059327373f},
        { 0.49039264020161522f,  0.41573480615127262f,  0.27778511650980114f,  0.09754516100806417f,
         -0.09754516100806417f, -0.27778511650980114f, -0.41573480615127262f, -0.49039264020161522f},
        { 0.46193976625564337f,  0.19134171618254492f, -0.19134171618254492f, -0.46193976625564337f,
         -0.46193976625564337f, -0.19134171618254492f,  0.19134171618254492f,  0.46193976625564337f},
        { 0.41573480615127262f, -0.09754516100806417f, -0.49039264020161522f, -0.27778511650980114f,
          0.27778511650980114f,  0.49039264020161522f,  0.09754516100806417f, -0.41573480615127262f},
        { 0.35355339059327373f, -0.35355339059327373f, -0.35355339059327373f,  0.35355339059327373f,
          0.35355339059327373f, -0.35355339059327373f, -0.35355339059327373f,  0.35355339059327373f},
        { 0.27778511650980114f, -0.49039264020161522f,  0.09754516100806417f,  0.41573480615127262f,
         -0.41573480615127262f, -0.09754516100806417f,  0.49039264020161522f, -0.27778511650980114f},
        { 0.19134171618254492f, -0.46193976625564337f,  0.46193976625564337f, -0.19134171618254492f,
         -0.19134171618254492f,  0.46193976625564337f, -0.46193976625564337f,  0.19134171618254492f},
        { 0.09754516100806417f, -0.27778511650980114f,  0.41573480615127262f, -0.49039264020161522f,
          0.49039264020161522f, -0.41573480615127262f,  0.27778511650980114f, -0.09754516100806417f},
    };

    __shared__ f32x4 lds4[2048];  // 32 KiB staging buffer (one half-phase)

    const int tl = threadIdx.x;
    const int t  = blockIdx.x * 256 + tl;

    // t -> (image n, block-row bi, block-col bj); 128x128 blocks per image
    const int n  = t >> 14;
    const int rm = t & 16383;
    const int bi = rm >> 7;
    const int bj = rm & 127;

    const float* src = x + (((size_t)n << 20) + ((size_t)bi << 13) + ((size_t)bj << 3));

    // Load row j, immediately fold into M = B * A^T (row j of M needs only
    // row j of B): M[j][m] = sum_l B[j][l] * A[m][l]
    float M[8][8];
#pragma unroll
    for (int j = 0; j < 8; ++j) {
        const f32x4 lo = *reinterpret_cast<const f32x4*>(src + (size_t)j * 1024);
        const f32x4 hi = *reinterpret_cast<const f32x4*>(src + (size_t)j * 1024 + 4);
        const float b[8] = {lo.x, lo.y, lo.z, lo.w, hi.x, hi.y, hi.z, hi.w};
#pragma unroll
        for (int m = 0; m < 8; ++m) {
            float acc = b[0] * A[m][0];
#pragma unroll
            for (int l = 1; l < 8; ++l) acc = fmaf(b[l], A[m][l], acc);
            M[j][m] = acc;
        }
    }

    // Workgroup w owns blocks [w*256, w*256+256) -> output floats [w*16384, ...).
    float* outw = out + ((size_t)blockIdx.x << 14);

    const int half = tl >> 7;   // wave-uniform: waves 0,1 -> half 0; waves 2,3 -> half 1
    const int tr   = tl & 127;  // rank within half

#pragma unroll
    for (int h = 0; h < 2; ++h) {
        if (half == h) {
            // C = A * M, row by row, straight into swizzled LDS.
#pragma unroll
            for (int i = 0; i < 8; ++i) {
                float c[8];
#pragma unroll
                for (int m = 0; m < 8; ++m) {
                    float acc = A[i][0] * M[0][m];
#pragma unroll
                    for (int j = 1; j < 8; ++j) acc = fmaf(A[i][j], M[j][m], acc);
                    c[m] = acc;
                }
                const int f0 = tr * 16 + i * 2;       // logical float4 index
                const int f1 = f0 + 1;
                f32x4 v0; v0.x = c[0]; v0.y = c[1]; v0.z = c[2]; v0.w = c[3];
                f32x4 v1; v1.x = c[4]; v1.y = c[5]; v1.z = c[6]; v1.w = c[7];
                lds4[f0 ^ (tr & 15)] = v0;
                lds4[f1 ^ (tr & 15)] = v1;
            }
        }
        __syncthreads();
        // Cooperative coalesced store: 2048 float4 = 32 KiB contiguous,
        // 256 threads x 16 B = 4 KiB per iteration. Nontemporal: output is
        // write-once -> keep it from evicting the L3-resident input.
        f32x4* dst4 = reinterpret_cast<f32x4*>(outw + h * 8192);
#pragma unroll
        for (int s = 0; s < 8; ++s) {
            const int f4 = s * 256 + tl;
            __builtin_nontemporal_store(lds4[f4 ^ ((f4 >> 4) & 15)], dst4 + f4);
        }
        if (h == 0) __syncthreads();  // protect LDS reuse by the second half-phase
    }
}

extern "C" void kernel_launch(void* const* d_in, const int* in_sizes, int n_in,
                              void* d_out, int out_size, void* d_ws, size_t ws_size,
                              hipStream_t stream) {
    const float* x = (const float*)d_in[0];
    float* out = (float*)d_out;

    const int nblocks = out_size / 64;        // 524288
    const int grid = nblocks / 256;           // 2048 workgroups, exact
    dct8x8_kernel<<<grid, 256, 0, stream>>>(x, out);
}

// Round 3
// 234.087 us; speedup vs baseline: 1.0139x; 1.0139x over previous
//
#include <hip/hip_runtime.h>

// 8x8 block DCT: C = A * B * A^T per non-overlapping block.
// R2: stores staged through LDS (32 KiB, two 128-thread half-phases) so global
// writes are fully coalesced 4 KiB/instruction; XOR-swizzled LDS (measured 0
// bank conflicts). Output stores nontemporal (write-once stream, keep input
// L3-resident).
// R5: VGPR_Count=48 proved the compiler sank the load+GEMM into the per-half
// guarded bodies (64-float M can't fit 48 regs) -> waves 2,3 issued their
// global loads only AFTER phase 0 completed (serialized, latency exposed) and
// ~8 floats/thread spilled (+16.5 MB WRITE_SIZE). Fix: accumulate C on the
// fly (row j of B -> row j of M -> rank-1 update of C) with 2-deep row
// prefetch, then PIN C into VGPRs with empty asm so the phase bodies are pure
// LDS writes and every load issues before the first barrier.

typedef float f32x4 __attribute__((ext_vector_type(4)));

__global__ __launch_bounds__(256, 5) void dct8x8_kernel(const float* __restrict__ x,
                                                        float* __restrict__ out) {
    constexpr float A[8][8] = {
        { 0.35355339059327373f,  0.35355339059327373f,  0.35355339059327373f,  0.35355339059327373f,
          0.35355339059327373f,  0.35355339059327373f,  0.35355339059327373f,  0.35355339059327373f},
        { 0.49039264020161522f,  0.41573480615127262f,  0.27778511650980114f,  0.09754516100806417f,
         -0.09754516100806417f, -0.27778511650980114f, -0.41573480615127262f, -0.49039264020161522f},
        { 0.46193976625564337f,  0.19134171618254492f, -0.19134171618254492f, -0.46193976625564337f,
         -0.46193976625564337f, -0.19134171618254492f,  0.19134171618254492f,  0.46193976625564337f},
        { 0.41573480615127262f, -0.09754516100806417f, -0.49039264020161522f, -0.27778511650980114f,
          0.27778511650980114f,  0.49039264020161522f,  0.09754516100806417f, -0.41573480615127262f},
        { 0.35355339059327373f, -0.35355339059327373f, -0.35355339059327373f,  0.35355339059327373f,
          0.35355339059327373f, -0.35355339059327373f, -0.35355339059327373f,  0.35355339059327373f},
        { 0.27778511650980114f, -0.49039264020161522f,  0.09754516100806417f,  0.41573480615127262f,
         -0.41573480615127262f, -0.09754516100806417f,  0.49039264020161522f, -0.27778511650980114f},
        { 0.19134171618254492f, -0.46193976625564337f,  0.46193976625564337f, -0.19134171618254492f,
         -0.19134171618254492f,  0.46193976625564337f, -0.46193976625564337f,  0.19134171618254492f},
        { 0.09754516100806417f, -0.27778511650980114f,  0.41573480615127262f, -0.49039264020161522f,
          0.49039264020161522f, -0.41573480615127262f,  0.27778511650980114f, -0.09754516100806417f},
    };

    __shared__ f32x4 lds4[2048];  // 32 KiB staging buffer (one half-phase)

    const int tl = threadIdx.x;
    const int t  = blockIdx.x * 256 + tl;

    // t -> (image n, block-row bi, block-col bj); 128x128 blocks per image
    const int n  = t >> 14;
    const int rm = t & 16383;
    const int bi = rm >> 7;
    const int bj = rm & 127;

    const float* src = x + (((size_t)n << 20) + ((size_t)bi << 13) + ((size_t)bj << 3));

    // Fused: for each input row j, fold into mj = rowj(B) * A^T, then rank-1
    // update C += A[:,j] (x) mj. 2-deep row prefetch keeps >=2 KiB/wave of
    // global loads in flight throughout.
    float c[64];
    f32x4 lo = *reinterpret_cast<const f32x4*>(src);
    f32x4 hi = *reinterpret_cast<const f32x4*>(src + 4);
#pragma unroll
    for (int j = 0; j < 8; ++j) {
        f32x4 nlo, nhi;
        if (j < 7) {
            nlo = *reinterpret_cast<const f32x4*>(src + (size_t)(j + 1) * 1024);
            nhi = *reinterpret_cast<const f32x4*>(src + (size_t)(j + 1) * 1024 + 4);
        }
        const float b[8] = {lo.x, lo.y, lo.z, lo.w, hi.x, hi.y, hi.z, hi.w};
        float mj[8];
#pragma unroll
        for (int m = 0; m < 8; ++m) {
            float acc = b[0] * A[m][0];
#pragma unroll
            for (int l = 1; l < 8; ++l) acc = fmaf(b[l], A[m][l], acc);
            mj[m] = acc;
        }
#pragma unroll
        for (int i = 0; i < 8; ++i) {
#pragma unroll
            for (int m = 0; m < 8; ++m) {
                c[i * 8 + m] = (j == 0) ? A[i][0] * mj[m]
                                        : fmaf(A[i][j], mj[m], c[i * 8 + m]);
            }
        }
        lo = nlo; hi = nhi;
    }

    // Pin C into VGPRs HERE: forbids the compiler from sinking the whole
    // load+compute chain into the per-half guarded bodies (which serialized
    // half-1's global loads behind phase 0 and caused scratch spills at R2's
    // 48-VGPR allocation).
#pragma unroll
    for (int i = 0; i < 64; ++i) asm volatile("" : "+v"(c[i]));

    // Workgroup w owns blocks [w*256, w*256+256) -> output floats [w*16384, ...).
    float* outw = out + ((size_t)blockIdx.x << 14);

    const int half = tl >> 7;   // wave-uniform: waves 0,1 -> half 0; waves 2,3 -> half 1
    const int tr   = tl & 127;  // rank within half

#pragma unroll
    for (int h = 0; h < 2; ++h) {
        if (half == h) {
            // Pure LDS writes (C already in regs), XOR-swizzled.
#pragma unroll
            for (int i = 0; i < 8; ++i) {
                const int f0 = tr * 16 + i * 2;       // logical float4 index
                const int f1 = f0 + 1;
                f32x4 v0; v0.x = c[i*8+0]; v0.y = c[i*8+1]; v0.z = c[i*8+2]; v0.w = c[i*8+3];
                f32x4 v1; v1.x = c[i*8+4]; v1.y = c[i*8+5]; v1.z = c[i*8+6]; v1.w = c[i*8+7];
                lds4[f0 ^ (tr & 15)] = v0;
                lds4[f1 ^ (tr & 15)] = v1;
            }
        }
        __syncthreads();
        // Cooperative coalesced store: 2048 float4 = 32 KiB contiguous,
        // 256 threads x 16 B = 4 KiB per iteration. Nontemporal: output is
        // write-once -> keep it from evicting the L3-resident input.
        f32x4* dst4 = reinterpret_cast<f32x4*>(outw + h * 8192);
#pragma unroll
        for (int s = 0; s < 8; ++s) {
            const int f4 = s * 256 + tl;
            __builtin_nontemporal_store(lds4[f4 ^ ((f4 >> 4) & 15)], dst4 + f4);
        }
        if (h == 0) __syncthreads();  // protect LDS reuse by the second half-phase
    }
}

extern "C" void kernel_launch(void* const* d_in, const int* in_sizes, int n_in,
                              void* d_out, int out_size, void* d_ws, size_t ws_size,
                              hipStream_t stream) {
    const float* x = (const float*)d_in[0];
    float* out = (float*)d_out;

    const int nblocks = out_size / 64;        // 524288
    const int grid = nblocks / 256;           // 2048 workgroups, exact
    dct8x8_kernel<<<grid, 256, 0, stream>>>(x, out);
}